// Round 1
// baseline (231.163 us; speedup 1.0000x reference)
//
#include <hip/hip_runtime.h>
#include <cmath>

#define HW 256
#define NIMG 48
#define NCH 3
#define NPLANE (NIMG * NCH)
#define STRIP 12          // output rows per block; STRIP+10 = 22 = exactly 2 ring chunks
#define NSTRIP 22         // 22*12 = 264 >= 256
#define NSLOT 64          // ws accumulator slots (kills atomic contention)

// ws doubles: ws[0..63] partial sums of (10*d + 10*l1 + 5*lw)
__global__ void zero_ws_kernel(double* ws) {
    if (threadIdx.x < NSLOT) ws[threadIdx.x] = 0.0;
}

// ---------------------------------------------------------------------------
// Fused SSIM + L1 + weighted-L1. One block = 12-row strip of one (n,c) plane.
// Separable 11x11 Gaussian: h-pass from LDS (11 rows staged per barrier),
// v-pass via an 11-slot register ring with compile-time cyclic indexing.
// vs previous version (STRIP=33, 1152 blocks, VGPR-capped 68):
//   - grid 1152 -> 3168 blocks (12.4/CU, ~3 residency rounds, small tail)
//   - __launch_bounds__(256,4): allow <=128 VGPR (same occupancy band as 68
//     per measured 64/128/256 steps) -> compiler can keep ring + prefetch live
//   - chunk-1 global loads issued into registers during chunk-0 compute
//   - pads zeroed once; 1 atomic/block into 64 scattered slots
// ---------------------------------------------------------------------------
__launch_bounds__(256, 4)
__global__ void fused_kernel(const float* __restrict__ pred,
                             const float* __restrict__ target,
                             const float* __restrict__ lmk,
                             double* __restrict__ ws)
{
    const int plane = blockIdx.x;          // n*3 + c
    const int n     = plane / 3;
    const int r0    = blockIdx.y * STRIP;
    const int x     = threadIdx.x;

    __shared__ float2 spt[11][HW + 10];    // (p,t) rows, 5-wide zero pads
    __shared__ float  sxc[STRIP][24];      // crossing x per (row, edge)
    __shared__ float  slm[48];             // landmarks 36..59 (x,y)
    __shared__ float  sbbs[12];            // per poly: xmin,xmax,ymin,ymax
    __shared__ float  svalids[3];
    __shared__ float  red[12];

    // Gaussian weights (same fp32 math as reference)
    float g[11];
    {
        float gs = 0.f;
#pragma unroll
        for (int i = 0; i < 11; ++i) {
            float c = (float)i - 5.0f;
            g[i] = expf(-c * c / 4.5f);
            gs += g[i];
        }
#pragma unroll
        for (int i = 0; i < 11; ++i) g[i] /= gs;
    }

    // ---- prologue: landmarks, pads (once), chunk-0 prefetch ---------------
    if (x < 48) slm[x] = lmk[n * 136 + 72 + x];
    if (x < 5) {
#pragma unroll
        for (int t = 0; t < 11; ++t) {
            spt[t][x]       = make_float2(0.f, 0.f);
            spt[t][261 + x] = make_float2(0.f, 0.f);
        }
    }

    const float* __restrict__ pp = pred   + (size_t)plane * (HW * HW);
    const float* __restrict__ tp = target + (size_t)plane * (HW * HW);

    // issue chunk-0 loads now so global latency overlaps the polygon prologue
    float2 pre[11];
#pragma unroll
    for (int t = 0; t < 11; ++t) {
        int r_in = r0 - 5 + t;
        float pv = 0.f, tv = 0.f;
        if (r_in >= 0 && r_in < HW) {
            pv = pp[r_in * HW + x];
            tv = tp[r_in * HW + x];
        }
        pre[t] = make_float2(pv, tv);
    }
    __syncthreads();   // slm ready

    if (x < 3) {
        const int s0 = (x == 0) ? 0 : (x == 1) ? 6 : 12;
        const int L  = (x == 2) ? 12 : 6;
        float xmn = 3e38f, xmx = -3e38f, ymn = 3e38f, ymx = -3e38f;
        for (int i = 0; i < L; ++i) {
            float px = slm[2 * (s0 + i)], py = slm[2 * (s0 + i) + 1];
            xmn = fminf(xmn, px); xmx = fmaxf(xmx, px);
            ymn = fminf(ymn, py); ymx = fmaxf(ymx, py);
        }
        xmn = floorf(xmn); xmx = floorf(xmx); ymn = floorf(ymn); ymx = floorf(ymx);
        sbbs[4 * x + 0] = xmn; sbbs[4 * x + 1] = xmx;
        sbbs[4 * x + 2] = ymn; sbbs[4 * x + 3] = ymx;
        svalids[x] = (xmn >= 0.f && ymn >= 0.f && xmx < 256.f && ymx < 256.f) ? 1.f : 0.f;
    }

#pragma unroll
    for (int u = 0; u < (STRIP * 24 + 255) / 256; ++u) {
        int idx = x + 256 * u;
        if (idx < STRIP * 24) {
            int r = idx / 24, e = idx - r * 24;
            float Y = (float)(r0 + r);
            const int s0 = (e < 6) ? 0 : (e < 12) ? 6 : 12;
            const int L  = (e < 12) ? 6 : 12;
            int il = e - s0;
            int i2 = (il + 1 == L) ? 0 : il + 1;
            float x1 = slm[2 * (s0 + il)], y1 = slm[2 * (s0 + il) + 1];
            float x2 = slm[2 * (s0 + i2)], y2 = slm[2 * (s0 + i2) + 1];
            bool crossing = (y1 > Y) != (y2 > Y);
            // exact reference fp32 expression order
            float xc = (x2 - x1) * (Y - y1) / (y2 - y1 + 1e-6f) + x1;
            sxc[r][e] = crossing ? xc : -3e38f;
        }
    }
    __syncthreads();

    // h-conv moment ring: slot = input_iter % 11, all indices compile-time
    float ring[11][5];
#pragma unroll
    for (int s = 0; s < 11; ++s)
#pragma unroll
        for (int q = 0; q < 5; ++q) ring[s][q] = 0.f;

    float acc = 0.f, accl1 = 0.f, acclw = 0.f;
    const float X = (float)x;

    // input rows r0-5 .. r0+16, exactly 2 chunks of 11
    for (int c = 0; c < 2; ++c) {
        // stage current chunk (pre[] -> LDS); previous chunk reads are done
        // (trailing barrier of prior iteration / prologue barrier)
#pragma unroll
        for (int t = 0; t < 11; ++t) {
            spt[t][x + 5] = pre[t];
        }
        __syncthreads();

        if (c == 0) {
            // prefetch chunk-1 rows into registers; waits land after compute
#pragma unroll
            for (int t = 0; t < 11; ++t) {
                int r_in = r0 + 6 + t;          // (r0 - 5 + 11 + t), >= 6 always
                float pv = 0.f, tv = 0.f;
                if (r_in < HW) {
                    pv = pp[r_in * HW + x];
                    tv = tp[r_in * HW + x];
                }
                pre[t] = make_float2(pv, tv);
            }
        }

#pragma unroll
        for (int t = 0; t < 11; ++t) {
            const int i = 11 * c + t;         // global input iteration
            const int r_in = r0 - 5 + i;

            // horizontal conv of the 5 moments; capture center tap (k==5)
            float h0 = 0.f, h1 = 0.f, h2 = 0.f, h3 = 0.f, h4 = 0.f;
            float2 center;
#pragma unroll
            for (int k = 0; k < 11; ++k) {
                float2 v = spt[t][x + k];
                if (k == 5) center = v;
                float w = g[k];
                float wp = w * v.x, wt = w * v.y;
                h0 += wp;
                h1 += wt;
                h2 = fmaf(wp, v.x, h2);
                h3 = fmaf(wt, v.y, h3);
                h4 = fmaf(wp, v.y, h4);
            }
            ring[t][0] = h0; ring[t][1] = h1; ring[t][2] = h2;
            ring[t][3] = h3; ring[t][4] = h4;

            // ---- L1 + weighted L1 for input row r_in (each row exactly once)
            if (i >= 5 && i < 5 + STRIP && r_in < HW) {
                float ad = fabsf(center.x - center.y);
                accl1 += ad;
                float Y = (float)r_in;
                float wgt = 1.f;
                bool any0 = (svalids[0] != 0.f) && (Y >= sbbs[2])  && (Y < sbbs[3]);
                bool any1 = (svalids[1] != 0.f) && (Y >= sbbs[6])  && (Y < sbbs[7]);
                bool any2 = (svalids[2] != 0.f) && (Y >= sbbs[10]) && (Y < sbbs[11]);
                if (any0 || any1 || any2) {   // wave-uniform branch
                    const float* xc = sxc[i - 5];
                    int c0 = 0, c1 = 0, c2 = 0;
#pragma unroll
                    for (int e = 0; e < 6; ++e)   c0 += (X < xc[e]) ? 1 : 0;
#pragma unroll
                    for (int e = 6; e < 12; ++e)  c1 += (X < xc[e]) ? 1 : 0;
#pragma unroll
                    for (int e = 12; e < 24; ++e) c2 += (X < xc[e]) ? 1 : 0;
                    if (any0 && (c0 & 1) && X >= sbbs[0] && X < sbbs[1]) wgt += 3.f;
                    if (any1 && (c1 & 1) && X >= sbbs[4] && X < sbbs[5]) wgt += 3.f;
                    if (any2 && (c2 & 1) && X >= sbbs[8] && X < sbbs[9]) wgt += 2.f;
                }
                acclw += wgt * ad;
            }

            // ---- SSIM output row r_out = r0 + i - 10 ------------------------
            if (i >= 10 && i < 10 + STRIP) {
                const int r_out = r0 + (i - 10);
                if (r_out < HW) {
                    float mux = 0.f, muy = 0.f, exx = 0.f, eyy = 0.f, exy = 0.f;
#pragma unroll
                    for (int j = 0; j < 11; ++j) {
                        const int s = (t + 1 + j) % 11;   // compile-time
                        float w = g[j];
                        mux = fmaf(w, ring[s][0], mux);
                        muy = fmaf(w, ring[s][1], muy);
                        exx = fmaf(w, ring[s][2], exx);
                        eyy = fmaf(w, ring[s][3], eyy);
                        exy = fmaf(w, ring[s][4], exy);
                    }
                    float sx  = exx - mux * mux;
                    float sy  = eyy - muy * muy;
                    float sxy = exy - mux * muy;
                    const float C1 = 1e-4f, C2 = 9e-4f;
                    float num = (2.f * mux * muy + C1) * (2.f * sxy + C2);
                    float den = (mux * mux + muy * muy + C1) * (sx + sy + C2);
                    acc += 0.5f * (1.f - num / (den + 1e-8f));
                }
            }
        }
        __syncthreads();   // this chunk's spt reads complete before restage
    }

    // ---- block reduction ---------------------------------------------------
#pragma unroll
    for (int off = 32; off > 0; off >>= 1) {
        acc   += __shfl_down(acc, off, 64);
        accl1 += __shfl_down(accl1, off, 64);
        acclw += __shfl_down(acclw, off, 64);
    }
    if ((x & 63) == 0) {
        int w = x >> 6;
        red[w] = acc; red[4 + w] = accl1; red[8 + w] = acclw;
    }
    __syncthreads();
    if (x == 0) {
        double s = 10.0 * ((double)red[0] + red[1] + red[2]  + red[3])
                 + 10.0 * ((double)red[4] + red[5] + red[6]  + red[7])
                 +  5.0 * ((double)red[8] + red[9] + red[10] + red[11]);
        atomicAdd(&ws[(blockIdx.y * NPLANE + blockIdx.x) & (NSLOT - 1)], s);
    }
}

// ---------------------------------------------------------------------------
__global__ void final_kernel(const double* __restrict__ ws, float* __restrict__ out) {
    double v = ws[threadIdx.x];
#pragma unroll
    for (int off = 32; off > 0; off >>= 1)
        v += __shfl_down(v, off, 64);
    if (threadIdx.x == 0) {
        const double denom = (double)NIMG * NCH * HW * HW;
        out[0] = (float)(v / denom);
    }
}

// ---------------------------------------------------------------------------
extern "C" void kernel_launch(void* const* d_in, const int* in_sizes, int n_in,
                              void* d_out, int out_size, void* d_ws, size_t ws_size,
                              hipStream_t stream)
{
    const float* pred   = (const float*)d_in[0];
    const float* target = (const float*)d_in[1];
    const float* lmk    = (const float*)d_in[2];
    float* out  = (float*)d_out;
    double* ws  = (double*)d_ws;

    hipLaunchKernelGGL(zero_ws_kernel, dim3(1), dim3(64), 0, stream, ws);
    hipLaunchKernelGGL(fused_kernel, dim3(NPLANE, NSTRIP), dim3(256), 0, stream,
                       pred, target, lmk, ws);
    hipLaunchKernelGGL(final_kernel, dim3(1), dim3(64), 0, stream, ws, out);
}

// Round 2
// 153.343 us; speedup vs baseline: 1.5075x; 1.5075x over previous
//
#include <hip/hip_runtime.h>
#include <cmath>

#define HW 256
#define NIMG 48
#define NCH 3
#define NPLANE (NIMG * NCH)
#define STRIP 37          // output rows per block; 144*7 = 1008 blocks <= 1024
#define NSTRIP 7          // 7*37 = 259 >= 256  -> ONE residency round, no tail
#define NIN (STRIP + 10)  // 47 input rows per block
#define NCHUNK 5          // ceil(47/11)
#define NSLOT 64          // ws accumulator slots

// ws doubles: ws[0..63] partial sums of (10*d + 10*l1 + 5*lw)
__global__ void zero_ws_kernel(double* ws) {
    if (threadIdx.x < NSLOT) ws[threadIdx.x] = 0.0;
}

// ---------------------------------------------------------------------------
// Fused SSIM + L1 + weighted-L1. One block = 37-row strip of one (n,c) plane.
// Separable 11x11 Gaussian: h-pass from LDS (11 rows staged per barrier),
// v-pass via an 11-slot register ring with compile-time cyclic indexing.
// Grid = 1008 blocks = 3.94 blocks/CU (VGPR~68 -> 4 waves/SIMD cap, LDS 27KB
// -> 5 blocks cap): whole grid resident in ONE round, no dispatch tail.
// Round-1 lesson: launch_bounds(256,4) + 22-reg prefetch => 64 VGPR + 203 MB
// of scratch spills. Reverted; plain __launch_bounds__(256), no reg prefetch.
// ---------------------------------------------------------------------------
__launch_bounds__(256)
__global__ void fused_kernel(const float* __restrict__ pred,
                             const float* __restrict__ target,
                             const float* __restrict__ lmk,
                             double* __restrict__ ws)
{
    const int plane = blockIdx.x;          // n*3 + c
    const int n     = plane / 3;
    const int r0    = blockIdx.y * STRIP;
    const int x     = threadIdx.x;

    __shared__ float2 spt[11][HW + 10];    // (p,t) rows, 5-wide zero pads
    __shared__ float  sxc[STRIP][24];      // crossing x per (row, edge)
    __shared__ float  slm[48];             // landmarks 36..59 (x,y)
    __shared__ float  sbbs[12];            // per poly: xmin,xmax,ymin,ymax
    __shared__ float  svalids[3];
    __shared__ float  red[12];

    // Gaussian weights (same fp32 math as reference)
    float g[11];
    {
        float gs = 0.f;
#pragma unroll
        for (int i = 0; i < 11; ++i) {
            float c = (float)i - 5.0f;
            g[i] = expf(-c * c / 4.5f);
            gs += g[i];
        }
#pragma unroll
        for (int i = 0; i < 11; ++i) g[i] /= gs;
    }

    // ---- prologue: landmarks, pads (once), bboxes, crossing table ----------
    if (x < 48) slm[x] = lmk[n * 136 + 72 + x];
    if (x < 5) {
#pragma unroll
        for (int t = 0; t < 11; ++t) {
            spt[t][x]       = make_float2(0.f, 0.f);
            spt[t][261 + x] = make_float2(0.f, 0.f);
        }
    }
    __syncthreads();

    if (x < 3) {
        const int s0 = (x == 0) ? 0 : (x == 1) ? 6 : 12;
        const int L  = (x == 2) ? 12 : 6;
        float xmn = 3e38f, xmx = -3e38f, ymn = 3e38f, ymx = -3e38f;
        for (int i = 0; i < L; ++i) {
            float px = slm[2 * (s0 + i)], py = slm[2 * (s0 + i) + 1];
            xmn = fminf(xmn, px); xmx = fmaxf(xmx, px);
            ymn = fminf(ymn, py); ymx = fmaxf(ymx, py);
        }
        xmn = floorf(xmn); xmx = floorf(xmx); ymn = floorf(ymn); ymx = floorf(ymx);
        sbbs[4 * x + 0] = xmn; sbbs[4 * x + 1] = xmx;
        sbbs[4 * x + 2] = ymn; sbbs[4 * x + 3] = ymx;
        svalids[x] = (xmn >= 0.f && ymn >= 0.f && xmx < 256.f && ymx < 256.f) ? 1.f : 0.f;
    }

#pragma unroll
    for (int u = 0; u < (STRIP * 24 + 255) / 256; ++u) {
        int idx = x + 256 * u;
        if (idx < STRIP * 24) {
            int r = idx / 24, e = idx - r * 24;
            float Y = (float)(r0 + r);
            const int s0 = (e < 6) ? 0 : (e < 12) ? 6 : 12;
            const int L  = (e < 12) ? 6 : 12;
            int il = e - s0;
            int i2 = (il + 1 == L) ? 0 : il + 1;
            float x1 = slm[2 * (s0 + il)], y1 = slm[2 * (s0 + il) + 1];
            float x2 = slm[2 * (s0 + i2)], y2 = slm[2 * (s0 + i2) + 1];
            bool crossing = (y1 > Y) != (y2 > Y);
            // exact reference fp32 expression order
            float xc = (x2 - x1) * (Y - y1) / (y2 - y1 + 1e-6f) + x1;
            sxc[r][e] = crossing ? xc : -3e38f;
        }
    }
    __syncthreads();

    float bb[12], sv[3];
#pragma unroll
    for (int q = 0; q < 12; ++q) bb[q] = sbbs[q];
#pragma unroll
    for (int q = 0; q < 3; ++q) sv[q] = svalids[q];

    const float* __restrict__ pp = pred   + (size_t)plane * (HW * HW);
    const float* __restrict__ tp = target + (size_t)plane * (HW * HW);

    // h-conv moment ring: slot = input_iter % 11, all indices compile-time
    float ring[11][5];
#pragma unroll
    for (int s = 0; s < 11; ++s)
#pragma unroll
        for (int q = 0; q < 5; ++q) ring[s][q] = 0.f;

    float acc = 0.f, accl1 = 0.f, acclw = 0.f;
    const float X = (float)x;

    // input rows r0-5 .. r0+41: 5 chunks of 11 stages, last 8 stages skipped
    for (int c = 0; c < NCHUNK; ++c) {
        __syncthreads();   // previous chunk's spt reads complete
#pragma unroll
        for (int t = 0; t < 11; ++t) {
            int i = 11 * c + t;
            if (i < NIN) {
                int r_in = r0 - 5 + i;
                float pv = 0.f, tv = 0.f;
                if (r_in >= 0 && r_in < HW) {
                    pv = pp[r_in * HW + x];
                    tv = tp[r_in * HW + x];
                }
                spt[t][x + 5] = make_float2(pv, tv);
            }
        }
        __syncthreads();

#pragma unroll
        for (int t = 0; t < 11; ++t) {
            const int i = 11 * c + t;         // global input iteration
            if (i >= NIN) continue;           // phantom stages of last chunk
            const int r_in = r0 - 5 + i;

            // horizontal conv of the 5 moments; capture center tap (k==5)
            float h0 = 0.f, h1 = 0.f, h2 = 0.f, h3 = 0.f, h4 = 0.f;
            float2 center;
#pragma unroll
            for (int k = 0; k < 11; ++k) {
                float2 v = spt[t][x + k];
                if (k == 5) center = v;
                float w = g[k];
                float wp = w * v.x, wt = w * v.y;
                h0 += wp;
                h1 += wt;
                h2 = fmaf(wp, v.x, h2);
                h3 = fmaf(wt, v.y, h3);
                h4 = fmaf(wp, v.y, h4);
            }
            ring[t][0] = h0; ring[t][1] = h1; ring[t][2] = h2;
            ring[t][3] = h3; ring[t][4] = h4;

            // ---- L1 + weighted L1 for input row r_in (each row exactly once)
            if (i >= 5 && i < 5 + STRIP && r_in < HW) {
                float ad = fabsf(center.x - center.y);
                accl1 += ad;
                float Y = (float)r_in;
                float wgt = 1.f;
                bool any0 = (sv[0] != 0.f) && (Y >= bb[2])  && (Y < bb[3]);
                bool any1 = (sv[1] != 0.f) && (Y >= bb[6])  && (Y < bb[7]);
                bool any2 = (sv[2] != 0.f) && (Y >= bb[10]) && (Y < bb[11]);
                if (any0 || any1 || any2) {   // wave-uniform branch
                    const float* xc = sxc[i - 5];
                    int c0 = 0, c1 = 0, c2 = 0;
#pragma unroll
                    for (int e = 0; e < 6; ++e)   c0 += (X < xc[e]) ? 1 : 0;
#pragma unroll
                    for (int e = 6; e < 12; ++e)  c1 += (X < xc[e]) ? 1 : 0;
#pragma unroll
                    for (int e = 12; e < 24; ++e) c2 += (X < xc[e]) ? 1 : 0;
                    if (any0 && (c0 & 1) && X >= bb[0] && X < bb[1]) wgt += 3.f;
                    if (any1 && (c1 & 1) && X >= bb[4] && X < bb[5]) wgt += 3.f;
                    if (any2 && (c2 & 1) && X >= bb[8] && X < bb[9]) wgt += 2.f;
                }
                acclw += wgt * ad;
            }

            // ---- SSIM output row r_out = r0 + i - 10 ------------------------
            if (i >= 10 && i < 10 + STRIP) {
                const int r_out = r0 + (i - 10);
                if (r_out < HW) {
                    float mux = 0.f, muy = 0.f, exx = 0.f, eyy = 0.f, exy = 0.f;
#pragma unroll
                    for (int j = 0; j < 11; ++j) {
                        const int s = (t + 1 + j) % 11;   // compile-time
                        float w = g[j];
                        mux = fmaf(w, ring[s][0], mux);
                        muy = fmaf(w, ring[s][1], muy);
                        exx = fmaf(w, ring[s][2], exx);
                        eyy = fmaf(w, ring[s][3], eyy);
                        exy = fmaf(w, ring[s][4], exy);
                    }
                    float sx  = exx - mux * mux;
                    float sy  = eyy - muy * muy;
                    float sxy = exy - mux * muy;
                    const float C1 = 1e-4f, C2 = 9e-4f;
                    float num = (2.f * mux * muy + C1) * (2.f * sxy + C2);
                    float den = (mux * mux + muy * muy + C1) * (sx + sy + C2);
                    acc += 0.5f * (1.f - num / (den + 1e-8f));
                }
            }
        }
    }

    // ---- block reduction ---------------------------------------------------
#pragma unroll
    for (int off = 32; off > 0; off >>= 1) {
        acc   += __shfl_down(acc, off, 64);
        accl1 += __shfl_down(accl1, off, 64);
        acclw += __shfl_down(acclw, off, 64);
    }
    if ((x & 63) == 0) {
        int w = x >> 6;
        red[w] = acc; red[4 + w] = accl1; red[8 + w] = acclw;
    }
    __syncthreads();
    if (x == 0) {
        double s = 10.0 * ((double)red[0] + red[1] + red[2]  + red[3])
                 + 10.0 * ((double)red[4] + red[5] + red[6]  + red[7])
                 +  5.0 * ((double)red[8] + red[9] + red[10] + red[11]);
        atomicAdd(&ws[(blockIdx.y * NPLANE + blockIdx.x) & (NSLOT - 1)], s);
    }
}

// ---------------------------------------------------------------------------
__global__ void final_kernel(const double* __restrict__ ws, float* __restrict__ out) {
    double v = ws[threadIdx.x];
#pragma unroll
    for (int off = 32; off > 0; off >>= 1)
        v += __shfl_down(v, off, 64);
    if (threadIdx.x == 0) {
        const double denom = (double)NIMG * NCH * HW * HW;
        out[0] = (float)(v / denom);
    }
}

// ---------------------------------------------------------------------------
extern "C" void kernel_launch(void* const* d_in, const int* in_sizes, int n_in,
                              void* d_out, int out_size, void* d_ws, size_t ws_size,
                              hipStream_t stream)
{
    const float* pred   = (const float*)d_in[0];
    const float* target = (const float*)d_in[1];
    const float* lmk    = (const float*)d_in[2];
    float* out  = (float*)d_out;
    double* ws  = (double*)d_ws;

    hipLaunchKernelGGL(zero_ws_kernel, dim3(1), dim3(64), 0, stream, ws);
    hipLaunchKernelGGL(fused_kernel, dim3(NPLANE, NSTRIP), dim3(256), 0, stream,
                       pred, target, lmk, ws);
    hipLaunchKernelGGL(final_kernel, dim3(1), dim3(64), 0, stream, ws, out);
}